// Round 7
// baseline (4194.850 us; speedup 1.0000x reference)
//
#include <hip/hip_runtime.h>
#include <math.h>

#define N_NODES    100000
#define K_NEIGH    32
#define OUT_STRIDE 448      // 3*128 + 64
#define NPASS      4
#define PRANGE     25000    // slab: 25000 rows * 128B = 3.2 MB < 4 MB per-XCD L2
#define ACC_GRID   1792     // co-resident: 7 blocks/CU * 256 CU (1-block/CU slack vs max 8)
#define NW         14       // nodes per wave: 1792*4*14 = 100352 >= 100000
#define N_PAD      100352   // padded node count for edge tables
#define PREP_NPB   128      // prep nodes per block

typedef __attribute__((ext_vector_type(8))) __bf16 bf16x8;
typedef __attribute__((ext_vector_type(4))) float  f32x4;

// bf16 helpers (RNE)
static __device__ __forceinline__ unsigned short f2bf(float f) {
    unsigned int u = __float_as_uint(f);
    return (unsigned short)((u + 0x7FFFu + ((u >> 16) & 1u)) >> 16);
}
static __device__ __forceinline__ float bf2f(unsigned short h) {
    return __uint_as_float(((unsigned int)h) << 16);
}

// ---------------------------------------------------------------------------
// Prep: per-node FULL SORT of edges by neighbor index j (sum/max are
// permutation-invariant -> legal). Sorted edges emitted PRE-DECODED:
//   jb[n][k] = j*128  (u32 byte offset of F row)   -> s_load, no bit decode
//   wf[n][k] = f32 weight                          -> s_load, feeds v_mul
// Rows [100000,100352) zero-filled: tail waves gather row 0 with weight 0.
// acc processes positions [8p,8p+8) during pass p: ~81% of gathers hit the
// pass-p slab with a fully static schedule.
// ---------------------------------------------------------------------------
__global__ __launch_bounds__(256) void prep_kernel(
    const float* __restrict__ dist, const int* __restrict__ idx,
    unsigned int* __restrict__ jb, float* __restrict__ wf,
    const float* __restrict__ W0, const float* __restrict__ W1,
    const float* __restrict__ W2,
    unsigned short* __restrict__ Wt0, unsigned short* __restrict__ Wt1,
    unsigned short* __restrict__ Wt2, unsigned int* __restrict__ bar)
{
    __shared__ unsigned int eLDS[PREP_NPB * 33];   // padded: bank-spread slices
    __shared__ float        dLDS[PREP_NPB * K_NEIGH];

    const int tid = threadIdx.x;
    const int gi  = blockIdx.x * 256 + tid;

    if (gi == 0) bar[0] = 0u;
    if (gi < 64 * 64)  Wt0[(gi & 63) * 64  + (gi >> 6)] = f2bf(W0[gi]);  // gi = k*64+n
    if (gi < 128 * 64) Wt1[(gi & 63) * 128 + (gi >> 6)] = f2bf(W1[gi]);
    if (gi < 128 * 64) Wt2[(gi & 63) * 128 + (gi >> 6)] = f2bf(W2[gi]);
    // zero-fill padded tail edge rows [N_NODES, N_PAD)
    if (gi < (N_PAD - N_NODES) * K_NEIGH) {
        jb[(size_t)N_NODES * K_NEIGH + gi] = 0u;
        wf[(size_t)N_NODES * K_NEIGH + gi] = 0.f;
    }

    const int nb0 = blockIdx.x * PREP_NPB;
    for (int t = tid; t < PREP_NPB * K_NEIGH; t += 256) {
        if (nb0 + (t >> 5) < N_NODES) {
            const size_t g = (size_t)nb0 * K_NEIGH + t;
            eLDS[(t >> 5) * 33 + (t & 31)] = (unsigned int)idx[g];
            dLDS[t] = dist[g];
        }
    }
    __syncthreads();

    if (tid < PREP_NPB && nb0 + tid < N_NODES) {
        const int base = tid * 33;
        for (int k = 0; k < K_NEIGH; ++k) {           // pack (j<<15)|w15
            const unsigned j = eLDS[base + k];
            const float w = __expf(-10.f * dLDS[tid * K_NEIGH + k]);
            const unsigned w15 = (unsigned)(w * 32767.f + 0.5f);
            eLDS[base + k] = (j << 15) | w15;
        }
        for (int k = 1; k < K_NEIGH; ++k) {           // insertion sort ascending
            const unsigned key = eLDS[base + k];
            int m = k - 1;
            while (m >= 0 && eLDS[base + m] > key) {
                eLDS[base + m + 1] = eLDS[base + m];
                --m;
            }
            eLDS[base + m + 1] = key;
        }
    }
    __syncthreads();

    for (int t = tid; t < PREP_NPB * K_NEIGH; t += 256) {
        if (nb0 + (t >> 5) < N_NODES) {
            const unsigned e = eLDS[(t >> 5) * 33 + (t & 31)];
            const size_t g = (size_t)nb0 * K_NEIGH + t;
            jb[g] = (e >> 15) << 7;                               // j * 128
            wf[g] = (float)(e & 0x7FFFu) * (1.f / 32767.f);
        }
    }
}

// ---------------------------------------------------------------------------
// Dense layer via MFMA (unchanged; F row-major [n][64] bf16).
// ---------------------------------------------------------------------------
template <int DIN, bool COPY_X>
__global__ __launch_bounds__(256) void dense_kernel(
    const float* __restrict__ in, int in_stride,
    const unsigned short* __restrict__ Wt,   // [64][DIN] bf16 (transposed W)
    const float* __restrict__ b,
    unsigned short* __restrict__ F, float* __restrict__ out)
{
    constexpr int LDK = DIN + 8;
    __shared__ unsigned short aLDS[64 * LDK];
    __shared__ unsigned short bLDS[64 * LDK];

    const int tid  = threadIdx.x;
    const int row0 = blockIdx.x * 64;

    for (int i = tid; i < 64 * (DIN / 4); i += 256) {
        const int r = i / (DIN / 4);
        const int c = (i % (DIN / 4)) * 4;
        const int n = row0 + r;
        float4 v = make_float4(0.f, 0.f, 0.f, 0.f);
        if (n < N_NODES) {
            v = *(const float4*)&in[(size_t)n * in_stride + c];
            if (COPY_X) *(float4*)&out[(size_t)n * OUT_STRIDE + 384 + c] = v;
        }
        const unsigned int u0 = (unsigned int)f2bf(v.x) | ((unsigned int)f2bf(v.y) << 16);
        const unsigned int u1 = (unsigned int)f2bf(v.z) | ((unsigned int)f2bf(v.w) << 16);
        *(uint2*)&aLDS[r * LDK + c] = make_uint2(u0, u1);
    }
    for (int i = tid; i < 64 * (DIN / 8); i += 256) {
        const int nn = i / (DIN / 8);
        const int k0 = (i % (DIN / 8)) * 8;
        *(uint4*)&bLDS[nn * LDK + k0] = *(const uint4*)&Wt[nn * DIN + k0];
    }
    __syncthreads();

    const int lane = tid & 63;
    const int wv   = tid >> 6;
    const int m    = lane & 15;
    const int quad = lane >> 4;

    f32x4 acc[4];
#pragma unroll
    for (int nb = 0; nb < 4; ++nb) acc[nb] = (f32x4){0.f, 0.f, 0.f, 0.f};

#pragma unroll
    for (int ks = 0; ks < DIN / 32; ++ks) {
        const int koff = ks * 32 + quad * 8;
        const bf16x8 afr =
            *reinterpret_cast<const bf16x8*>(&aLDS[(wv * 16 + m) * LDK + koff]);
#pragma unroll
        for (int nb = 0; nb < 4; ++nb) {
            const bf16x8 bfr =
                *reinterpret_cast<const bf16x8*>(&bLDS[(nb * 16 + m) * LDK + koff]);
            acc[nb] = __builtin_amdgcn_mfma_f32_16x16x32_bf16(afr, bfr, acc[nb], 0, 0, 0);
        }
    }

#pragma unroll
    for (int nb = 0; nb < 4; ++nb) {
        const int c    = nb * 16 + m;
        const float bc = b[c];
#pragma unroll
        for (int reg = 0; reg < 4; ++reg) {
            const int n = row0 + wv * 16 + quad * 4 + reg;
            if (n < N_NODES) {
                const float vv = fmaxf(acc[nb][reg] + bc, 0.f);
                F[(size_t)n * 64 + c] = f2bf(vv);
            }
        }
    }
}

// ---------------------------------------------------------------------------
// KNN accumulate v8: phased residency + SPILL-PROOF engine.
//   Fix vs v7 (rule #20): node loop FULLY unrolled -> sum/mx statically
//   indexed -> registers, never scratch.
//   Fix vs v6 (budget): NW=14 -> 28 acc VGPRs; total demand ~55-60 fits even
//   a 64-VGPR allocation. 1792 blocks * 4 waves * 14 = 100352 node slots;
//   tail slots gather zero-filled edge rows (row 0, weight 0), stores guarded.
//   Gather form: uniform row pointer (SGPR pair, s_add on SALU) + shared
//   lane*2 voffset -> 1 VGPR per in-flight gather result.
//   Occupancy: 7 blocks/CU (launch_bounds(256,7) -> ~72 VGPR budget),
//   1792 co-resident with 1-block/CU slack -> barrier safe; ~28 waves/CU
//   gives ~2x the latency hiding of the 417us baseline.
//   Barrier: proven ticket design; s_sleep(32); bounded spin (degrade-only).
// ---------------------------------------------------------------------------
__global__ __launch_bounds__(256, 7) void acc_kernel(
    const unsigned short* __restrict__ F,
    const unsigned int* __restrict__ jb,   // [N_PAD][32] sorted j*128
    const float* __restrict__ wf,          // [N_PAD][32] sorted weights f32
    float* __restrict__ out,               // already offset to layer slab
    unsigned int* __restrict__ bar)
{
    const int tid  = threadIdx.x;
    const int lane = tid & 63;
    const int wid  = __builtin_amdgcn_readfirstlane(blockIdx.x * 4 + (tid >> 6));
    const int n0   = wid * NW;

    const unsigned int* __restrict__ jrow = jb + (size_t)n0 * K_NEIGH; // uniform
    const float*        __restrict__ wrow = wf + (size_t)n0 * K_NEIGH; // uniform
    const char*         __restrict__ Fb   = (const char*)F;

    float sum[NW], mx[NW];
#pragma unroll
    for (int i = 0; i < NW; ++i) { sum[i] = 0.f; mx[i] = -INFINITY; }

    for (int p = 0; p < NPASS; ++p) {
#pragma unroll
        for (int i = 0; i < NW; ++i) {
            const unsigned int* __restrict__ jp = jrow + i * K_NEIGH + p * 8;
            const float*        __restrict__ wp = wrow + i * K_NEIGH + p * 8;
            float g[8];
#pragma unroll
            for (int t = 0; t < 8; ++t) {
                // uniform row pointer (SGPR pair) + lane*2 voffset: 1 VGPR in flight
                const unsigned short* __restrict__ rowp =
                    (const unsigned short*)(Fb + jp[t]);
                g[t] = bf2f(rowp[lane]);
            }
#pragma unroll
            for (int t = 0; t < 8; ++t) {
                const float v = wp[t] * g[t];          // v_mul (SGPR weight)
                sum[i] += v;
                mx[i]  = fmaxf(mx[i], v);
            }
        }
        if (p < NPASS - 1) {
            __syncthreads();
            if (tid == 0) {
                const unsigned tk = __hip_atomic_fetch_add(
                    bar, 1u, __ATOMIC_ACQ_REL, __HIP_MEMORY_SCOPE_AGENT);
                const unsigned target = (tk / ACC_GRID + 1u) * ACC_GRID;
                int spins = 0;
                while (__hip_atomic_load(bar, __ATOMIC_ACQUIRE,
                                         __HIP_MEMORY_SCOPE_AGENT) < target) {
                    __builtin_amdgcn_s_sleep(32);     // ~853ns poll: low contention
                    if (++spins > 1000) break;        // failsafe: degrade, never hang
                }
            }
            __syncthreads();
        }
    }

    // Epilogue: prev rows sequential per wave -> coalesced streaming reads.
#pragma unroll
    for (int i = 0; i < NW; ++i) {
        const int n = n0 + i;
        if (n < N_NODES) {
            const float prev = bf2f(F[(size_t)n * 64 + lane]);
            float* orow = out + (size_t)n * OUT_STRIDE + lane;
            __builtin_nontemporal_store(sum[i] * (1.f / 32.f) - prev, orow);
            __builtin_nontemporal_store(mx[i] - prev, orow + 64);
        }
    }
}

// ---------------------------------------------------------------------------
extern "C" void kernel_launch(void* const* d_in, const int* in_sizes, int n_in,
                              void* d_out, int out_size, void* d_ws, size_t ws_size,
                              hipStream_t stream)
{
    const float* x    = (const float*)d_in[0];
    const int*   idx  = (const int*)  d_in[1];
    const float* dist = (const float*)d_in[2];
    const float* W0   = (const float*)d_in[3];
    const float* b0   = (const float*)d_in[4];
    const float* W1   = (const float*)d_in[5];
    const float* b1   = (const float*)d_in[6];
    const float* W2   = (const float*)d_in[7];
    const float* b2   = (const float*)d_in[8];

    float* out = (float*)d_out;

    // Workspace layout (all 16B-aligned). Edge tables padded to N_PAD rows.
    char* ws = (char*)d_ws;
    unsigned short* F    = (unsigned short*)(ws);                 // 12.8 MB
    unsigned int*   jbuf = (unsigned int*)  (ws + 12800000);      // 12.85 MB
    float*          wbuf = (float*)         (ws + 25645056);      // 12.85 MB
    unsigned short* Wt0  = (unsigned short*)(ws + 38490112);      // 8 KB
    unsigned short* Wt1  = (unsigned short*)(ws + 38498304);      // 16 KB
    unsigned short* Wt2  = (unsigned short*)(ws + 38514688);      // 16 KB
    unsigned int*   bar  = (unsigned int*)  (ws + 38531072);      // 4 B

    const int prep_grid  = (N_NODES + PREP_NPB - 1) / PREP_NPB;  // 782
    const int dense_grid = (N_NODES + 63) / 64;                  // 1563

    prep_kernel<<<prep_grid, 256, 0, stream>>>(dist, idx, jbuf, wbuf,
                                               W0, W1, W2, Wt0, Wt1, Wt2, bar);

    // Layer 0: dense from x (also copies x into out[:,384:448])
    dense_kernel<64, true><<<dense_grid, 256, 0, stream>>>(x, 64, Wt0, b0, F, out);
    acc_kernel<<<ACC_GRID, 256, 0, stream>>>(F, jbuf, wbuf, out + 0, bar);

    // Layer 1: dense reads layer-0 slab of out (it IS the next input)
    dense_kernel<128, false><<<dense_grid, 256, 0, stream>>>(out + 0, OUT_STRIDE, Wt1, b1, F, nullptr);
    acc_kernel<<<ACC_GRID, 256, 0, stream>>>(F, jbuf, wbuf, out + 128, bar);

    // Layer 2
    dense_kernel<128, false><<<dense_grid, 256, 0, stream>>>(out + 128, OUT_STRIDE, Wt2, b2, F, nullptr);
    acc_kernel<<<ACC_GRID, 256, 0, stream>>>(F, jbuf, wbuf, out + 256, bar);
}

// Round 8
// 3761.234 us; speedup vs baseline: 1.1153x; 1.1153x over previous
//
#include <hip/hip_runtime.h>
#include <math.h>

#define N_NODES    100000
#define K_NEIGH    32
#define OUT_STRIDE 448      // 3*128 + 64
#define NPASS      4
#define PRANGE     25000    // slab: 25000 rows * 128B = 3.2 MB < 4 MB per-XCD L2
#define ACC_GRID   1280     // needs 5 blocks/CU; launch_bounds guarantees 6 -> slack
#define NW         20       // nodes per wave: 1280*4*20 = 102400 >= 100000
#define N_PAD      102400   // padded node count for edge tables
#define PREP_NPB   128      // prep nodes per block

typedef __attribute__((ext_vector_type(8))) __bf16 bf16x8;
typedef __attribute__((ext_vector_type(4))) float  f32x4;

// bf16 helpers (RNE)
static __device__ __forceinline__ unsigned short f2bf(float f) {
    unsigned int u = __float_as_uint(f);
    return (unsigned short)((u + 0x7FFFu + ((u >> 16) & 1u)) >> 16);
}
static __device__ __forceinline__ float bf2f(unsigned short h) {
    return __uint_as_float(((unsigned int)h) << 16);
}

// ---------------------------------------------------------------------------
// Prep: per-node FULL SORT of edges by neighbor index j (sum/max are
// permutation-invariant -> legal). Sorted edges emitted PRE-DECODED:
//   jb[n][k] = j*128  (u32 byte offset of F row)   -> s_load, no bit decode
//   wf[n][k] = f32 weight                          -> s_load, feeds v_mul
// Rows [100000,102400) zero-filled: tail slots gather row 0 with weight 0.
// acc processes positions [8p,8p+8) during pass p: ~81% of gathers hit the
// pass-p slab with a fully static schedule.
// ---------------------------------------------------------------------------
__global__ __launch_bounds__(256) void prep_kernel(
    const float* __restrict__ dist, const int* __restrict__ idx,
    unsigned int* __restrict__ jb, float* __restrict__ wf,
    const float* __restrict__ W0, const float* __restrict__ W1,
    const float* __restrict__ W2,
    unsigned short* __restrict__ Wt0, unsigned short* __restrict__ Wt1,
    unsigned short* __restrict__ Wt2, unsigned int* __restrict__ bar)
{
    __shared__ unsigned int eLDS[PREP_NPB * 33];   // padded: bank-spread slices
    __shared__ float        dLDS[PREP_NPB * K_NEIGH];

    const int tid = threadIdx.x;
    const int gi  = blockIdx.x * 256 + tid;

    if (gi == 0) bar[0] = 0u;
    if (gi < 64 * 64)  Wt0[(gi & 63) * 64  + (gi >> 6)] = f2bf(W0[gi]);  // gi = k*64+n
    if (gi < 128 * 64) Wt1[(gi & 63) * 128 + (gi >> 6)] = f2bf(W1[gi]);
    if (gi < 128 * 64) Wt2[(gi & 63) * 128 + (gi >> 6)] = f2bf(W2[gi]);
    // zero-fill padded tail edge rows [N_NODES, N_PAD)
    if (gi < (N_PAD - N_NODES) * K_NEIGH) {
        jb[(size_t)N_NODES * K_NEIGH + gi] = 0u;
        wf[(size_t)N_NODES * K_NEIGH + gi] = 0.f;
    }

    const int nb0 = blockIdx.x * PREP_NPB;
    for (int t = tid; t < PREP_NPB * K_NEIGH; t += 256) {
        if (nb0 + (t >> 5) < N_NODES) {
            const size_t g = (size_t)nb0 * K_NEIGH + t;
            eLDS[(t >> 5) * 33 + (t & 31)] = (unsigned int)idx[g];
            dLDS[t] = dist[g];
        }
    }
    __syncthreads();

    if (tid < PREP_NPB && nb0 + tid < N_NODES) {
        const int base = tid * 33;
        for (int k = 0; k < K_NEIGH; ++k) {           // pack (j<<15)|w15
            const unsigned j = eLDS[base + k];
            const float w = __expf(-10.f * dLDS[tid * K_NEIGH + k]);
            const unsigned w15 = (unsigned)(w * 32767.f + 0.5f);
            eLDS[base + k] = (j << 15) | w15;
        }
        for (int k = 1; k < K_NEIGH; ++k) {           // insertion sort ascending
            const unsigned key = eLDS[base + k];
            int m = k - 1;
            while (m >= 0 && eLDS[base + m] > key) {
                eLDS[base + m + 1] = eLDS[base + m];
                --m;
            }
            eLDS[base + m + 1] = key;
        }
    }
    __syncthreads();

    for (int t = tid; t < PREP_NPB * K_NEIGH; t += 256) {
        if (nb0 + (t >> 5) < N_NODES) {
            const unsigned e = eLDS[(t >> 5) * 33 + (t & 31)];
            const size_t g = (size_t)nb0 * K_NEIGH + t;
            jb[g] = (e >> 15) << 7;                               // j * 128
            wf[g] = (float)(e & 0x7FFFu) * (1.f / 32767.f);
        }
    }
}

// ---------------------------------------------------------------------------
// Dense layer via MFMA (unchanged; F row-major [n][64] bf16).
// ---------------------------------------------------------------------------
template <int DIN, bool COPY_X>
__global__ __launch_bounds__(256) void dense_kernel(
    const float* __restrict__ in, int in_stride,
    const unsigned short* __restrict__ Wt,   // [64][DIN] bf16 (transposed W)
    const float* __restrict__ b,
    unsigned short* __restrict__ F, float* __restrict__ out)
{
    constexpr int LDK = DIN + 8;
    __shared__ unsigned short aLDS[64 * LDK];
    __shared__ unsigned short bLDS[64 * LDK];

    const int tid  = threadIdx.x;
    const int row0 = blockIdx.x * 64;

    for (int i = tid; i < 64 * (DIN / 4); i += 256) {
        const int r = i / (DIN / 4);
        const int c = (i % (DIN / 4)) * 4;
        const int n = row0 + r;
        float4 v = make_float4(0.f, 0.f, 0.f, 0.f);
        if (n < N_NODES) {
            v = *(const float4*)&in[(size_t)n * in_stride + c];
            if (COPY_X) *(float4*)&out[(size_t)n * OUT_STRIDE + 384 + c] = v;
        }
        const unsigned int u0 = (unsigned int)f2bf(v.x) | ((unsigned int)f2bf(v.y) << 16);
        const unsigned int u1 = (unsigned int)f2bf(v.z) | ((unsigned int)f2bf(v.w) << 16);
        *(uint2*)&aLDS[r * LDK + c] = make_uint2(u0, u1);
    }
    for (int i = tid; i < 64 * (DIN / 8); i += 256) {
        const int nn = i / (DIN / 8);
        const int k0 = (i % (DIN / 8)) * 8;
        *(uint4*)&bLDS[nn * LDK + k0] = *(const uint4*)&Wt[nn * DIN + k0];
    }
    __syncthreads();

    const int lane = tid & 63;
    const int wv   = tid >> 6;
    const int m    = lane & 15;
    const int quad = lane >> 4;

    f32x4 acc[4];
#pragma unroll
    for (int nb = 0; nb < 4; ++nb) acc[nb] = (f32x4){0.f, 0.f, 0.f, 0.f};

#pragma unroll
    for (int ks = 0; ks < DIN / 32; ++ks) {
        const int koff = ks * 32 + quad * 8;
        const bf16x8 afr =
            *reinterpret_cast<const bf16x8*>(&aLDS[(wv * 16 + m) * LDK + koff]);
#pragma unroll
        for (int nb = 0; nb < 4; ++nb) {
            const bf16x8 bfr =
                *reinterpret_cast<const bf16x8*>(&bLDS[(nb * 16 + m) * LDK + koff]);
            acc[nb] = __builtin_amdgcn_mfma_f32_16x16x32_bf16(afr, bfr, acc[nb], 0, 0, 0);
        }
    }

#pragma unroll
    for (int nb = 0; nb < 4; ++nb) {
        const int c    = nb * 16 + m;
        const float bc = b[c];
#pragma unroll
        for (int reg = 0; reg < 4; ++reg) {
            const int n = row0 + wv * 16 + quad * 4 + reg;
            if (n < N_NODES) {
                const float vv = fmaxf(acc[nb][reg] + bc, 0.f);
                F[(size_t)n * 64 + c] = f2bf(vv);
            }
        }
    }
}

// ---------------------------------------------------------------------------
// KNN accumulate v9: phased residency + ARRAY-FREE engine.
//   v6/v7/v8 all died to the same failure class: C-array accumulators that
//   the allocator demoted to scratch (rule #20 / occupancy squeeze). v9 has
//   NO arrays: all 40 accumulators and all 8 gather temps are macro-generated
//   NAMED SCALARS -> cannot be runtime-indexed -> cannot go to scratch.
//   Demand ~60 VGPR fits even a 64-VGPR budget.
//   Gather form: uniform edge words via s_load (K$); addr = SGPR base+offset
//   (SALU fold) + shared lane*2 voffset -> 1 VGPR per in-flight gather.
//   Grid 1280 needs 5 blocks/CU; launch_bounds(256,6) guarantees 6 -> slack
//   against uneven dispatch. Ticket barrier (proven), s_sleep(32), bounded
//   spin failsafe (degrade-only, phasing is perf-only).
// ---------------------------------------------------------------------------
#define FOR_NODES(X) \
    X(0) X(1) X(2) X(3) X(4) X(5) X(6) X(7) X(8) X(9) \
    X(10) X(11) X(12) X(13) X(14) X(15) X(16) X(17) X(18) X(19)

__global__ __launch_bounds__(256, 6) void acc_kernel(
    const unsigned short* __restrict__ F,
    const unsigned int* __restrict__ jb,   // [N_PAD][32] sorted j*128
    const float* __restrict__ wf,          // [N_PAD][32] sorted weights f32
    float* __restrict__ out,               // already offset to layer slab
    unsigned int* __restrict__ bar)
{
    const int tid  = threadIdx.x;
    const int lane = tid & 63;
    const int wid  = __builtin_amdgcn_readfirstlane(blockIdx.x * 4 + (tid >> 6));
    const int n0   = wid * NW;

    const unsigned int* __restrict__ jrow = jb + (size_t)n0 * K_NEIGH; // uniform
    const float*        __restrict__ wrow = wf + (size_t)n0 * K_NEIGH; // uniform
    const char*         __restrict__ Fb   = (const char*)F;
    const unsigned lane2 = (unsigned)lane * 2u;

#define DECL_ACC(i) float s##i = 0.f, q##i = -INFINITY;
    FOR_NODES(DECL_ACC)
#undef DECL_ACC

    for (int p = 0; p < NPASS; ++p) {
        const int p8 = p * 8;
#define NODE_BODY(i) { \
        const unsigned int* __restrict__ jp = jrow + (i) * K_NEIGH + p8; \
        const float*        __restrict__ wp = wrow + (i) * K_NEIGH + p8; \
        const unsigned b0 = jp[0], b1 = jp[1], b2 = jp[2], b3 = jp[3], \
                       b4 = jp[4], b5 = jp[5], b6 = jp[6], b7 = jp[7]; \
        const float w0 = wp[0], w1 = wp[1], w2 = wp[2], w3 = wp[3], \
                    w4 = wp[4], w5 = wp[5], w6 = wp[6], w7 = wp[7]; \
        const float g0 = bf2f(*(const unsigned short*)(Fb + b0 + lane2)); \
        const float g1 = bf2f(*(const unsigned short*)(Fb + b1 + lane2)); \
        const float g2 = bf2f(*(const unsigned short*)(Fb + b2 + lane2)); \
        const float g3 = bf2f(*(const unsigned short*)(Fb + b3 + lane2)); \
        const float g4 = bf2f(*(const unsigned short*)(Fb + b4 + lane2)); \
        const float g5 = bf2f(*(const unsigned short*)(Fb + b5 + lane2)); \
        const float g6 = bf2f(*(const unsigned short*)(Fb + b6 + lane2)); \
        const float g7 = bf2f(*(const unsigned short*)(Fb + b7 + lane2)); \
        float v; \
        v = w0 * g0; s##i += v; q##i = fmaxf(q##i, v); \
        v = w1 * g1; s##i += v; q##i = fmaxf(q##i, v); \
        v = w2 * g2; s##i += v; q##i = fmaxf(q##i, v); \
        v = w3 * g3; s##i += v; q##i = fmaxf(q##i, v); \
        v = w4 * g4; s##i += v; q##i = fmaxf(q##i, v); \
        v = w5 * g5; s##i += v; q##i = fmaxf(q##i, v); \
        v = w6 * g6; s##i += v; q##i = fmaxf(q##i, v); \
        v = w7 * g7; s##i += v; q##i = fmaxf(q##i, v); }
        FOR_NODES(NODE_BODY)
#undef NODE_BODY

        if (p < NPASS - 1) {
            __syncthreads();
            if (tid == 0) {
                const unsigned tk = __hip_atomic_fetch_add(
                    bar, 1u, __ATOMIC_ACQ_REL, __HIP_MEMORY_SCOPE_AGENT);
                const unsigned target = (tk / ACC_GRID + 1u) * ACC_GRID;
                int spins = 0;
                while (__hip_atomic_load(bar, __ATOMIC_ACQUIRE,
                                         __HIP_MEMORY_SCOPE_AGENT) < target) {
                    __builtin_amdgcn_s_sleep(32);     // ~853ns poll: low contention
                    if (++spins > 1000) break;        // failsafe: degrade, never hang
                }
            }
            __syncthreads();
        }
    }

    // Epilogue: prev rows sequential per wave -> coalesced streaming reads.
#define EPI(i) { \
        const int n = n0 + (i); \
        if (n < N_NODES) { \
            const float prev = bf2f(F[(size_t)n * 64 + lane]); \
            float* orow = out + (size_t)n * OUT_STRIDE + lane; \
            __builtin_nontemporal_store(s##i * (1.f / 32.f) - prev, orow); \
            __builtin_nontemporal_store(q##i - prev, orow + 64); } }
    FOR_NODES(EPI)
#undef EPI
}

// ---------------------------------------------------------------------------
extern "C" void kernel_launch(void* const* d_in, const int* in_sizes, int n_in,
                              void* d_out, int out_size, void* d_ws, size_t ws_size,
                              hipStream_t stream)
{
    const float* x    = (const float*)d_in[0];
    const int*   idx  = (const int*)  d_in[1];
    const float* dist = (const float*)d_in[2];
    const float* W0   = (const float*)d_in[3];
    const float* b0   = (const float*)d_in[4];
    const float* W1   = (const float*)d_in[5];
    const float* b1   = (const float*)d_in[6];
    const float* W2   = (const float*)d_in[7];
    const float* b2   = (const float*)d_in[8];

    float* out = (float*)d_out;

    // Workspace layout (all 16B-aligned). Edge tables padded to N_PAD rows.
    char* ws = (char*)d_ws;
    unsigned short* F    = (unsigned short*)(ws);                 // 12.8 MB
    unsigned int*   jbuf = (unsigned int*)  (ws + 12800000);      // 13.1 MB
    float*          wbuf = (float*)         (ws + 25907200);      // 13.1 MB
    unsigned short* Wt0  = (unsigned short*)(ws + 39014400);      // 8 KB
    unsigned short* Wt1  = (unsigned short*)(ws + 39022592);      // 16 KB
    unsigned short* Wt2  = (unsigned short*)(ws + 39038976);      // 16 KB
    unsigned int*   bar  = (unsigned int*)  (ws + 39055360);      // 4 B

    const int prep_grid  = (N_NODES + PREP_NPB - 1) / PREP_NPB;  // 782
    const int dense_grid = (N_NODES + 63) / 64;                  // 1563

    prep_kernel<<<prep_grid, 256, 0, stream>>>(dist, idx, jbuf, wbuf,
                                               W0, W1, W2, Wt0, Wt1, Wt2, bar);

    // Layer 0: dense from x (also copies x into out[:,384:448])
    dense_kernel<64, true><<<dense_grid, 256, 0, stream>>>(x, 64, Wt0, b0, F, out);
    acc_kernel<<<ACC_GRID, 256, 0, stream>>>(F, jbuf, wbuf, out + 0, bar);

    // Layer 1: dense reads layer-0 slab of out (it IS the next input)
    dense_kernel<128, false><<<dense_grid, 256, 0, stream>>>(out + 0, OUT_STRIDE, Wt1, b1, F, nullptr);
    acc_kernel<<<ACC_GRID, 256, 0, stream>>>(F, jbuf, wbuf, out + 128, bar);

    // Layer 2
    dense_kernel<128, false><<<dense_grid, 256, 0, stream>>>(out + 128, OUT_STRIDE, Wt2, b2, F, nullptr);
    acc_kernel<<<ACC_GRID, 256, 0, stream>>>(F, jbuf, wbuf, out + 256, bar);
}